// Round 2
// baseline (369.222 us; speedup 1.0000x reference)
//
#include <hip/hip_runtime.h>
#include <hip/hip_bf16.h>
#include <math.h>

// x[32,1024,2048] f32, W[1024,1024] f32, b[1024] f32, out[32,1024] f32.
#define BB 32
#define CC 1024
#define LL 2048

// Kernel 1: s[b,c] = sum_l x[b,c,l]. Persistent grid: 2048 blocks x 256 thr
// = 8192 waves; each wave grid-strides over 4 of the 32768 rows.
// Per row: 64 lanes x 8 float4 coalesced loads (8 KB), wave shuffle-reduce.
__global__ __launch_bounds__(256) void sum_rows_kernel(
    const float* __restrict__ x, float* __restrict__ s) {
    const int lane   = threadIdx.x & 63;
    const int wid0   = (blockIdx.x * blockDim.x + threadIdx.x) >> 6;
    const int nwaves = (gridDim.x * blockDim.x) >> 6;
    for (int row = wid0; row < BB * CC; row += nwaves) {
        const float4* p = reinterpret_cast<const float4*>(x + (size_t)row * LL);
        // issue all 8 loads before consuming (max memory-level parallelism)
        float4 v0 = p[lane +   0], v1 = p[lane +  64];
        float4 v2 = p[lane + 128], v3 = p[lane + 192];
        float4 v4 = p[lane + 256], v5 = p[lane + 320];
        float4 v6 = p[lane + 384], v7 = p[lane + 448];
        float4 a;
        a.x = v0.x + v1.x + v2.x + v3.x + v4.x + v5.x + v6.x + v7.x;
        a.y = v0.y + v1.y + v2.y + v3.y + v4.y + v5.y + v6.y + v7.y;
        a.z = v0.z + v1.z + v2.z + v3.z + v4.z + v5.z + v6.z + v7.z;
        a.w = v0.w + v1.w + v2.w + v3.w + v4.w + v5.w + v6.w + v7.w;
        float acc = (a.x + a.y) + (a.z + a.w);
#pragma unroll
        for (int off = 32; off > 0; off >>= 1) acc += __shfl_down(acc, off);
        if (lane == 0) s[row] = acc;
    }
}

// Kernel 2: y[b,o] = dot(W[o,:], s[b,:]) + L*bias[o]; out = mish(y).
// One wave per 4 outputs (same b): s[b,:] loaded into regs once, reused.
__global__ __launch_bounds__(256) void gemm_mish_kernel(
    const float* __restrict__ s, const float* __restrict__ W,
    const float* __restrict__ bias, float* __restrict__ out) {
    const int lane = threadIdx.x & 63;
    const int gw   = (blockIdx.x * blockDim.x + threadIdx.x) >> 6;
    if (gw >= BB * CC / 4) return;
    const int bb = gw >> 8;          // batch index (256 groups per batch)
    const int og = (gw & 255) * 4;   // first of 4 output channels
    const float4* sp = reinterpret_cast<const float4*>(s + (size_t)bb * CC);
    float4 s0 = sp[lane +   0], s1 = sp[lane +  64];
    float4 s2 = sp[lane + 128], s3 = sp[lane + 192];
#pragma unroll
    for (int k = 0; k < 4; ++k) {
        const int oo = og + k;
        const float4* wp = reinterpret_cast<const float4*>(W + (size_t)oo * CC);
        float4 w0 = wp[lane +   0], w1 = wp[lane +  64];
        float4 w2 = wp[lane + 128], w3 = wp[lane + 192];
        float acc = w0.x * s0.x + w0.y * s0.y + w0.z * s0.z + w0.w * s0.w
                  + w1.x * s1.x + w1.y * s1.y + w1.z * s1.z + w1.w * s1.w
                  + w2.x * s2.x + w2.y * s2.y + w2.z * s2.z + w2.w * s2.w
                  + w3.x * s3.x + w3.y * s3.y + w3.z * s3.z + w3.w * s3.w;
#pragma unroll
        for (int off = 32; off > 0; off >>= 1) acc += __shfl_down(acc, off);
        if (lane == 0) {
            float y = acc + (float)LL * bias[oo];
            float sp_ = (y > 20.0f) ? y : log1pf(expf(y));
            out[(size_t)bb * CC + oo] = y * tanhf(sp_);
        }
    }
}

extern "C" void kernel_launch(void* const* d_in, const int* in_sizes, int n_in,
                              void* d_out, int out_size, void* d_ws, size_t ws_size,
                              hipStream_t stream) {
    const float* x    = (const float*)d_in[0];
    const float* W    = (const float*)d_in[1];
    const float* bias = (const float*)d_in[2];
    float* out        = (float*)d_out;
    float* s          = (float*)d_ws;  // 32*1024 f32 = 128 KB scratch

    // Kernel 1: persistent grid, 2048 blocks (8 blocks/CU), grid-stride rows.
    sum_rows_kernel<<<2048, 256, 0, stream>>>(x, s);
    // Kernel 2: 8192 wave-groups (4 outputs each) -> 2048 blocks.
    gemm_mish_kernel<<<2048, 256, 0, stream>>>(s, W, bias, out);
}

// Round 4
// 342.246 us; speedup vs baseline: 1.0788x; 1.0788x over previous
//
#include <hip/hip_runtime.h>
#include <hip/hip_bf16.h>
#include <math.h>

// x[32,1024,2048] f32, W[1024,1024] f32, b[1024] f32, out[32,1024] f32.
#define BB 32
#define CC 1024
#define LL 2048

typedef float f32x4 __attribute__((ext_vector_type(4)));

// Kernel 1: s[b,c] = sum_l x[b,c,l]. Persistent grid: 2048 blocks x 256 thr
// = 8192 waves; each wave grid-strides over 4 of the 32768 rows.
// Non-temporal loads: x has zero reuse, keep it out of L2 (W/s stay warm).
__global__ __launch_bounds__(256) void sum_rows_kernel(
    const float* __restrict__ x, float* __restrict__ s) {
    const int lane   = threadIdx.x & 63;
    const int wid0   = (blockIdx.x * blockDim.x + threadIdx.x) >> 6;
    const int nwaves = (gridDim.x * blockDim.x) >> 6;
    for (int row = wid0; row < BB * CC; row += nwaves) {
        const f32x4* p = reinterpret_cast<const f32x4*>(x + (size_t)row * LL);
        // issue all 8 loads before consuming (max memory-level parallelism)
        f32x4 v0 = __builtin_nontemporal_load(&p[lane +   0]);
        f32x4 v1 = __builtin_nontemporal_load(&p[lane +  64]);
        f32x4 v2 = __builtin_nontemporal_load(&p[lane + 128]);
        f32x4 v3 = __builtin_nontemporal_load(&p[lane + 192]);
        f32x4 v4 = __builtin_nontemporal_load(&p[lane + 256]);
        f32x4 v5 = __builtin_nontemporal_load(&p[lane + 320]);
        f32x4 v6 = __builtin_nontemporal_load(&p[lane + 384]);
        f32x4 v7 = __builtin_nontemporal_load(&p[lane + 448]);
        f32x4 a = (v0 + v1) + (v2 + v3);
        f32x4 b = (v4 + v5) + (v6 + v7);
        f32x4 t = a + b;
        float acc = (t.x + t.y) + (t.z + t.w);
#pragma unroll
        for (int off = 32; off > 0; off >>= 1) acc += __shfl_down(acc, off);
        if (lane == 0) s[row] = acc;
    }
}

// Kernel 2: y[b,o] = dot(W[o,:], s[b,:]) + L*bias[o]; out = mish(y).
// One wave per 4 outputs (same b): s[b,:] loaded into regs once, reused.
__global__ __launch_bounds__(256) void gemm_mish_kernel(
    const float* __restrict__ s, const float* __restrict__ W,
    const float* __restrict__ bias, float* __restrict__ out) {
    const int lane = threadIdx.x & 63;
    const int gw   = (blockIdx.x * blockDim.x + threadIdx.x) >> 6;
    if (gw >= BB * CC / 4) return;
    const int bb = gw >> 8;          // batch index (256 groups per batch)
    const int og = (gw & 255) * 4;   // first of 4 output channels
    const f32x4* sp = reinterpret_cast<const f32x4*>(s + (size_t)bb * CC);
    f32x4 s0 = sp[lane +   0], s1 = sp[lane +  64];
    f32x4 s2 = sp[lane + 128], s3 = sp[lane + 192];
#pragma unroll
    for (int k = 0; k < 4; ++k) {
        const int oo = og + k;
        const f32x4* wp = reinterpret_cast<const f32x4*>(W + (size_t)oo * CC);
        f32x4 w0 = wp[lane +   0], w1 = wp[lane +  64];
        f32x4 w2 = wp[lane + 128], w3 = wp[lane + 192];
        f32x4 m = w0 * s0 + w1 * s1 + w2 * s2 + w3 * s3;
        float acc = (m.x + m.y) + (m.z + m.w);
#pragma unroll
        for (int off = 32; off > 0; off >>= 1) acc += __shfl_down(acc, off);
        if (lane == 0) {
            float y = acc + (float)LL * bias[oo];
            float sp_ = (y > 20.0f) ? y : log1pf(expf(y));
            out[(size_t)bb * CC + oo] = y * tanhf(sp_);
        }
    }
}

extern "C" void kernel_launch(void* const* d_in, const int* in_sizes, int n_in,
                              void* d_out, int out_size, void* d_ws, size_t ws_size,
                              hipStream_t stream) {
    const float* x    = (const float*)d_in[0];
    const float* W    = (const float*)d_in[1];
    const float* bias = (const float*)d_in[2];
    float* out        = (float*)d_out;
    float* s          = (float*)d_ws;  // 32*1024 f32 = 128 KB scratch

    // Kernel 1: persistent grid, 2048 blocks (8 blocks/CU), grid-stride rows.
    sum_rows_kernel<<<2048, 256, 0, stream>>>(x, s);
    // Kernel 2: 8192 wave-groups (4 outputs each) -> 2048 blocks.
    gemm_mish_kernel<<<2048, 256, 0, stream>>>(s, W, bias, out);
}